// Round 18
// baseline (2303.644 us; speedup 1.0000x reference)
//
#include <hip/hip_runtime.h>
#include <math.h>

#define BATCH  64
#define TSTEPS 2048
#define EMBED  300
#define HID    256
#define GATES  1024  // 4*HID
#define WSTRIDE 36   // dwords per W-LDS row: 16B-aligned rows -> b128 reads;
                     // banks (4l+4c)%32 distinct within each 8-lane phase
#define ASTR   328   // f16 stride of k_gemm staged tiles (300 data + 28 pad)

typedef __fp16 h2 __attribute__((ext_vector_type(2)));   // matches cvt_pkrtz/fdot2
typedef __fp16 h4 __attribute__((ext_vector_type(4)));
typedef __fp16 h8 __attribute__((ext_vector_type(8)));
typedef float  f4 __attribute__((ext_vector_type(4)));

__device__ __forceinline__ h2 pack_h2(float a, float b) {
    return __builtin_amdgcn_cvt_pkrtz(a, b);
}
__device__ __forceinline__ h2 bc_h2(unsigned u) {
    return __builtin_bit_cast(h2, u);
}
__device__ __forceinline__ float dot2f(h2 w, h2 h, float acc) {
#if __has_builtin(__builtin_amdgcn_fdot2)
    return __builtin_amdgcn_fdot2(w, h, acc, false);   // f32 accumulate
#else
    return acc + (float)w[0]*(float)h[0] + (float)w[1]*(float)h[1];
#endif
}
__device__ __forceinline__ float rcpf_(float x) {
#if __has_builtin(__builtin_amdgcn_rcpf)
    return __builtin_amdgcn_rcpf(x);
#else
    return 1.0f / x;
#endif
}
__device__ __forceinline__ float sigm_(float x) { return rcpf_(1.f + __expf(-x)); }
__device__ __forceinline__ float tanh_(float x) { return 1.f - 2.f*rcpf_(__expf(2.f*x) + 1.f); }

// ---------------- Kernel 1: per-chunk compaction of update steps ------------
__global__ __launch_bounds__(256) void k_compact(
    const float* __restrict__ mask, const int* __restrict__ lengths,
    int* __restrict__ list, int* __restrict__ cnt,
    float* __restrict__ h_state, float* __restrict__ c_state,
    int t0, int CT, int first_chunk)
{
    int b = blockIdx.x, tid = threadIdx.x;
    if (first_chunk) {
        h_state[b*HID + tid] = 0.f;   // blockDim == HID
        c_state[b*HID + tid] = 0.f;
    }
    int idx = lengths[b] - 1;
    idx = idx < 0 ? 0 : (idx > TSTEPS-1 ? TSTEPS-1 : idx);

    __shared__ int wcnt[4];
    __shared__ int running;
    if (tid == 0) running = 0;
    __syncthreads();

    for (int base = 0; base < CT; base += 256) {
        int t = t0 + base + tid;
        bool pred = ((base + tid) < CT) && (t <= idx)
                    && (mask[b*TSTEPS + t] >= 0.5f);
        unsigned long long bal = __ballot(pred);
        int wave = tid >> 6, lane = tid & 63;
        if (lane == 0) wcnt[wave] = __popcll(bal);
        __syncthreads();
        int off = running;
        for (int w2 = 0; w2 < wave; ++w2) off += wcnt[w2];
        off += __popcll(bal & ((1ull << lane) - 1ull));
        if (pred) list[b*CT + off] = t;
        __syncthreads();
        if (tid == 0) running += wcnt[0] + wcnt[1] + wcnt[2] + wcnt[3];
        __syncthreads();
    }
    if (tid == 0) cnt[b] = running;
}

// ---------------- Kernel 2: gathered GEMM via MFMA, persistent-B ------------
// r14 structure; ONE change: Z written as f16 (halves the 267MB f32 write
// stream — the largest single memory stream of the bandwidth-bound kernel;
// Z is now fully L3-resident in both directions). |z| <= ~1.5, f16 rel err
// 2^-11 — negligible vs the f16 W/h already in the pipeline.
__global__ __launch_bounds__(256) void k_gemm(
    const float* __restrict__ emb, const float* __restrict__ W_ih,
    const int* __restrict__ list, const int* __restrict__ cnt,
    _Float16* __restrict__ Z, int CT)
{
    int b = blockIdx.z;
    int mb = cnt[b];
    int n0 = blockIdx.x * 128;
    int tid = threadIdx.x;
    int w = tid >> 6, l = tid & 63;

    __shared__ _Float16 Al[64 * ASTR];     // 41,984 B
    __shared__ _Float16 Bl[128 * ASTR];    // 83,968 B
    __shared__ int tl[64];

    for (int idx = tid; idx < 128*75; idx += 256) {
        int r = idx / 75, c = idx - 75*r;
        float4 v = ((const float4*)(W_ih + (size_t)(n0 + r)*EMBED))[c];
        *(h2*)&Bl[r*ASTR + 4*c]     = pack_h2(v.x, v.y);
        *(h2*)&Bl[r*ASTR + 4*c + 2] = pack_h2(v.z, v.w);
    }
    for (int idx = tid; idx < 128*14; idx += 256) {
        int r = idx / 14, c2 = idx - 14*r;
        *(unsigned*)&Bl[r*ASTR + 300 + 2*c2] = 0u;
    }
    for (int idx = tid; idx < 64*14; idx += 256) {
        int r = idx / 14, c2 = idx - 14*r;
        *(unsigned*)&Al[r*ASTR + 300 + 2*c2] = 0u;   // pad written once
    }

    int arow = w*16 + (l & 15);
    int kg4  = (l >> 4) * 4;
    int drow0 = w*16 + (l >> 4)*4;

    for (int i0 = 0; i0 < mb; i0 += 64) {
        __syncthreads();           // prev MFMA done -> Al/tl reusable; B ready
        if (tid < 64) {
            int j = i0 + tid;
            tl[tid] = (j < mb) ? list[b*CT + j] : -1;
        }
        __syncthreads();           // tl visible
        for (int idx = tid; idx < 64*75; idx += 256) {
            int r = idx / 75, c = idx - 75*r;
            float4 v = {0.f, 0.f, 0.f, 0.f};
            int trow = tl[r];
            if (trow >= 0)
                v = ((const float4*)(emb + ((size_t)b*TSTEPS + trow)*EMBED))[c];
            *(h2*)&Al[r*ASTR + 4*c]     = pack_h2(v.x, v.y);
            *(h2*)&Al[r*ASTR + 4*c + 2] = pack_h2(v.z, v.w);
        }
        __syncthreads();           // Al visible

        f4 acc[8];
        #pragma unroll
        for (int nt = 0; nt < 8; ++nt) acc[nt] = f4{0.f, 0.f, 0.f, 0.f};

        #pragma unroll 2
        for (int ks = 0; ks < 10; ++ks) {
            int kb = ks*32 + kg4;
            h4 alo = *(const h4*)&Al[arow*ASTR + kb];
            h4 ahi = *(const h4*)&Al[arow*ASTR + kb + 16];
            h8 af = __builtin_shufflevector(alo, ahi, 0,1,2,3,4,5,6,7);
            #pragma unroll
            for (int nt = 0; nt < 8; ++nt) {
                int brow = nt*16 + (l & 15);
                h4 blo = *(const h4*)&Bl[brow*ASTR + kb];
                h4 bhi = *(const h4*)&Bl[brow*ASTR + kb + 16];
                h8 bf = __builtin_shufflevector(blo, bhi, 0,1,2,3,4,5,6,7);
                acc[nt] = __builtin_amdgcn_mfma_f32_16x16x32_f16(af, bf, acc[nt], 0, 0, 0);
            }
        }

        #pragma unroll
        for (int nt = 0; nt < 8; ++nt) {
            #pragma unroll
            for (int j = 0; j < 4; ++j) {
                int r = drow0 + j;
                if (i0 + r < mb)
                    Z[((size_t)b*CT + i0 + r)*GATES + n0 + nt*16 + (l & 15)] =
                        (_Float16)acc[nt][j];
            }
        }
    }
}

// ---------------- Kernel 3: recurrent LSTM — ONE block per batch ------------
// r17 structure (measured 1735us: 192 h2 AGPR + k<64 LDS b128 WSTRIDE=36,
// 2 barriers, native activations). ONLY change: z loads are f16 (Z stream
// halved; edit confined to the z-load lines, W arrays untouched).
__global__ __launch_bounds__(512, 2) void k_lstm(
    const _Float16* __restrict__ Z, const int* __restrict__ cnt,
    const float* __restrict__ W_hh,
    const float* __restrict__ b_ih, const float* __restrict__ b_hh,
    float* __restrict__ h_state, float* __restrict__ c_state, int CT)
{
    int b = blockIdx.x;
    int tid = threadIdx.x;            // 0..511
    int d   = tid & 255;              // hidden dim this thread's rows act on
    int rowA = tid;                   // gate (tid>>8)      : 0 or 1
    int rowB = tid + 512;             // gate (tid>>8) + 2  : 2 or 3

    __shared__ __align__(16) unsigned wlds[1024 * WSTRIDE];  // 147,456 B
    __shared__ float act13[2][256];                  // forget, out broadcast
    __shared__ __align__(16) _Float16 h_arr[HID];    // current h (f16)

    // ---- stage W[k<64] into LDS as f16 pairs --------------------------------
    for (int idx = tid; idx < 1024*32; idx += 512) {
        int r = idx >> 5, k = idx & 31;              // k = half2 index (f16 2k,2k+1)
        float2 v = ((const float2*)(W_hh + (size_t)r*HID))[k];
        *(h2*)&wlds[r*WSTRIDE + k] = pack_h2(v.x, v.y);
    }

    // ---- W[k in 64..255] into registers: 96 half2 per row -------------------
    h2 wrA[96], wrB[96];
    {
        const float2* pA = (const float2*)(W_hh + (size_t)rowA*HID);
        const float2* pB = (const float2*)(W_hh + (size_t)rowB*HID);
        #pragma unroll
        for (int t = 0; t < 96; ++t) {
            float2 va = pA[32 + t], vb = pB[32 + t];
            wrA[t] = pack_h2(va.x, va.y);
            wrB[t] = pack_h2(vb.x, vb.y);
        }
    }
    float biasA = b_ih[rowA] + b_hh[rowA];
    float biasB = b_ih[rowB] + b_hh[rowB];

    float c_reg = 0.f;
    if (tid < 256) {
        h_arr[d] = (_Float16)h_state[(size_t)b*HID + d];
        c_reg    = c_state[(size_t)b*HID + d];
    }
    __syncthreads();

    int mb = cnt[b];
    float zAcur = 0.f, zBcur = 0.f;
    if (mb > 0) {
        zAcur = (float)Z[((size_t)b*CT)*GATES + rowA];
        zBcur = (float)Z[((size_t)b*CT)*GATES + rowB];
    }

    for (int j = 0; j < mb; ++j) {
        // prefetch next step's z under the dot
        float zAn = 0.f, zBn = 0.f;
        if (j + 1 < mb) {
            zAn = (float)Z[((size_t)b*CT + j + 1)*GATES + rowA];
            zBn = (float)Z[((size_t)b*CT + j + 1)*GATES + rowB];
        }

        float accA0 = 0.f, accA1 = 0.f, accB0 = 0.f, accB1 = 0.f;
        #pragma unroll
        for (int c = 0; c < 32; ++c) {
            uint4 hv = ((const uint4*)h_arr)[c];     // 8 f16 of h (broadcast)
            h2 h0 = bc_h2(hv.x), h1 = bc_h2(hv.y);
            h2 h2_ = bc_h2(hv.z), h3 = bc_h2(hv.w);
            h2 wA0, wA1, wA2, wA3, wB0, wB1, wB2, wB3;
            if (c < 8) {
                uint4 wa = *(const uint4*)&wlds[rowA*WSTRIDE + 4*c];   // b128
                uint4 wb = *(const uint4*)&wlds[rowB*WSTRIDE + 4*c];   // b128
                wA0 = bc_h2(wa.x); wA1 = bc_h2(wa.y);
                wA2 = bc_h2(wa.z); wA3 = bc_h2(wa.w);
                wB0 = bc_h2(wb.x); wB1 = bc_h2(wb.y);
                wB2 = bc_h2(wb.z); wB3 = bc_h2(wb.w);
            } else {
                int t = (c - 8) * 4;
                wA0 = wrA[t+0]; wA1 = wrA[t+1]; wA2 = wrA[t+2]; wA3 = wrA[t+3];
                wB0 = wrB[t+0]; wB1 = wrB[t+1]; wB2 = wrB[t+2]; wB3 = wrB[t+3];
            }
            accA0 = dot2f(wA0, h0, accA0);
            accA1 = dot2f(wA1, h1, accA1);
            accA0 = dot2f(wA2, h2_, accA0);
            accA1 = dot2f(wA3, h3, accA1);
            accB0 = dot2f(wB0, h0, accB0);
            accB1 = dot2f(wB1, h1, accB1);
            accB0 = dot2f(wB2, h2_, accB0);
            accB1 = dot2f(wB3, h3, accB1);
        }
        float aF = zAcur + biasA + (accA0 + accA1);   // gate input(i<256)/forget
        float aS = zBcur + biasB + (accB0 + accB1);   // gate cellcand / out

        float iv = 0.f, gv = 0.f;
        if (tid < 256) {
            iv = sigm_(aF);                 // input gate
            gv = tanh_(aS);                 // cell candidate
        } else {
            act13[0][d] = sigm_(aF);        // forget gate
            act13[1][d] = sigm_(aS);        // output gate
        }
        __syncthreads();   // act13 ready; everyone done reading h_arr

        if (tid < 256) {
            float fv = act13[0][d], ov = act13[1][d];
            c_reg = fv * c_reg + iv * gv;
            float hn = ov * tanh_(c_reg);
            h_arr[d] = (_Float16)hn;
        }
        __syncthreads();   // h_arr ready for next step
        zAcur = zAn; zBcur = zBn;
    }

    if (tid < 256) {
        h_state[(size_t)b*HID + d] = (float)h_arr[d];
        c_state[(size_t)b*HID + d] = c_reg;
    }
}

// ---------------- Kernel 4: logits -> softmax -> argmax ---------------------
__global__ __launch_bounds__(64) void k_final(
    const float* __restrict__ h_state, const float* __restrict__ W_out,
    const float* __restrict__ b_out, float* __restrict__ out)
{
    int b = threadIdx.x;   // 64 threads
    float l0 = b_out[0], l1 = b_out[1];
    for (int k = 0; k < HID; ++k) {
        float h = h_state[b*HID + k];
        l0 += h * W_out[k];
        l1 += h * W_out[HID + k];
    }
    float m  = fmaxf(l0, l1);
    float e0 = expf(l0 - m), e1 = expf(l1 - m);
    float s  = e0 + e1;
    float p0 = e0 / s, p1 = e1 / s;
    out[b*2 + 0] = p0;
    out[b*2 + 1] = p1;
    out[BATCH*2 + b] = (p1 > p0) ? 1.0f : 0.0f;  // argmax, first-index tiebreak
}

// ---------------- host ------------------------------------------------------
extern "C" void kernel_launch(void* const* d_in, const int* in_sizes, int n_in,
                              void* d_out, int out_size, void* d_ws, size_t ws_size,
                              hipStream_t stream)
{
    (void)in_sizes; (void)n_in; (void)out_size;
    const float* emb   = (const float*)d_in[0];
    const float* mask  = (const float*)d_in[1];
    const int*   len   = (const int*)  d_in[2];
    const float* W_ih  = (const float*)d_in[3];
    const float* W_hh  = (const float*)d_in[4];
    const float* b_ih  = (const float*)d_in[5];
    const float* b_hh  = (const float*)d_in[6];
    const float* W_out = (const float*)d_in[7];
    const float* b_out = (const float*)d_in[8];
    float* out = (float*)d_out;

    char* p = (char*)d_ws;
    auto carve = [&](size_t bytes) -> char* {
        char* r = p;
        p += (bytes + 255) & ~(size_t)255;
        return r;
    };
    float* h_state = (float*)carve((size_t)BATCH*HID*4);
    float* c_state = (float*)carve((size_t)BATCH*HID*4);
    int*   cntb    = (int*)  carve((size_t)BATCH*4);

    size_t fixed = (size_t)(p - (char*)d_ws);
    int CT = TSTEPS;  // shrink to fit workspace
    while (CT > 64) {
        size_t lb = (((size_t)BATCH*CT*4) + 255) & ~(size_t)255;
        size_t zb = (size_t)BATCH*CT*GATES*2;     // Z is f16 now
        if (fixed + lb + zb + 1024 <= ws_size) break;
        CT >>= 1;
    }
    int*      list = (int*)     carve((size_t)BATCH*CT*4);
    _Float16* Z    = (_Float16*)carve((size_t)BATCH*CT*GATES*2);

    int nchunks = TSTEPS / CT;
    for (int c = 0; c < nchunks; ++c) {
        int t0 = c * CT;
        int first = (c == 0) ? 1 : 0;
        hipLaunchKernelGGL(k_compact, dim3(BATCH), dim3(256), 0, stream,
                           mask, len, list, cntb, h_state, c_state,
                           t0, CT, first);
        hipLaunchKernelGGL(k_gemm, dim3(8, 1, BATCH), dim3(256), 0, stream,
                           emb, W_ih, list, cntb, Z, CT);
        hipLaunchKernelGGL(k_lstm, dim3(BATCH), dim3(512), 0, stream,
                           Z, cntb, W_hh, b_ih, b_hh,
                           h_state, c_state, CT);
    }
    hipLaunchKernelGGL(k_final, dim3(1), dim3(64), 0, stream,
                       h_state, W_out, b_out, out);
}

// Round 19
// 2129.368 us; speedup vs baseline: 1.0818x; 1.0818x over previous
//
#include <hip/hip_runtime.h>
#include <math.h>

#define BATCH  64
#define TSTEPS 2048
#define EMBED  300
#define HID    256
#define GATES  1024  // 4*HID
#define WSTRIDE 36   // dwords per W-LDS row (b128-aligned, conflict-free)
#define ASTR   328   // f16 stride of gemm staged tiles (300 data + 28 pad)
#define NWORK  192   // gemm worker blocks (256 total - 64 lstm)
#define SHDW   37504 // shared dwords = 150,016 B (same as r17 lstm footprint)

typedef __fp16 h2 __attribute__((ext_vector_type(2)));
typedef __fp16 h4 __attribute__((ext_vector_type(4)));
typedef __fp16 h8 __attribute__((ext_vector_type(8)));
typedef float  f4 __attribute__((ext_vector_type(4)));

__device__ __forceinline__ h2 pack_h2(float a, float b) {
    return __builtin_amdgcn_cvt_pkrtz(a, b);
}
__device__ __forceinline__ h2 bc_h2(unsigned u) {
    return __builtin_bit_cast(h2, u);
}
__device__ __forceinline__ float dot2f(h2 w, h2 h, float acc) {
#if __has_builtin(__builtin_amdgcn_fdot2)
    return __builtin_amdgcn_fdot2(w, h, acc, false);
#else
    return acc + (float)w[0]*(float)h[0] + (float)w[1]*(float)h[1];
#endif
}
__device__ __forceinline__ float rcpf_(float x) {
#if __has_builtin(__builtin_amdgcn_rcpf)
    return __builtin_amdgcn_rcpf(x);
#else
    return 1.0f / x;
#endif
}
__device__ __forceinline__ float sigm_(float x) { return rcpf_(1.f + __expf(-x)); }
__device__ __forceinline__ float tanh_(float x) { return 1.f - 2.f*rcpf_(__expf(2.f*x) + 1.f); }

__device__ __forceinline__ void spin_tile(const int* f) {
    int tries = 0;
    while (__hip_atomic_load(f, __ATOMIC_ACQUIRE, __HIP_MEMORY_SCOPE_AGENT) < 8) {
        __builtin_amdgcn_s_sleep(4);
        if (++tries > (1 << 18)) break;   // degrade, never wedge
    }
}

// ---------------- Kernel 1: compaction + ready-flag zeroing -----------------
__global__ __launch_bounds__(256) void k_compact(
    const float* __restrict__ mask, const int* __restrict__ lengths,
    int* __restrict__ list, int* __restrict__ cnt, int* __restrict__ ready,
    float* __restrict__ h_state, float* __restrict__ c_state,
    int t0, int CT, int first_chunk)
{
    int b = blockIdx.x, tid = threadIdx.x;
    if (first_chunk) {
        h_state[b*HID + tid] = 0.f;   // blockDim == HID
        c_state[b*HID + tid] = 0.f;
    }
    if (tid < 32) ready[b*32 + tid] = 0;
    int idx = lengths[b] - 1;
    idx = idx < 0 ? 0 : (idx > TSTEPS-1 ? TSTEPS-1 : idx);

    __shared__ int wcnt[4];
    __shared__ int running;
    if (tid == 0) running = 0;
    __syncthreads();

    for (int base = 0; base < CT; base += 256) {
        int t = t0 + base + tid;
        bool pred = ((base + tid) < CT) && (t <= idx)
                    && (mask[b*TSTEPS + t] >= 0.5f);
        unsigned long long bal = __ballot(pred);
        int wave = tid >> 6, lane = tid & 63;
        if (lane == 0) wcnt[wave] = __popcll(bal);
        __syncthreads();
        int off = running;
        for (int w2 = 0; w2 < wave; ++w2) off += wcnt[w2];
        off += __popcll(bal & ((1ull << lane) - 1ull));
        if (pred) list[b*CT + off] = t;
        __syncthreads();
        if (tid == 0) running += wcnt[0] + wcnt[1] + wcnt[2] + wcnt[3];
        __syncthreads();
    }
    if (tid == 0) cnt[b] = running;
}

// ---------------- Kernel 2: FUSED producer/consumer -------------------------
// grid 256 x 512thr, 1 block/CU (150KB LDS), all co-resident (r3-verified).
// Blocks 0..63: r17 lstm (hot loop byte-equivalent, Z f32) + per-64-step
// ACQUIRE poll of ready[b][m]. Blocks 64..255: gemm workers producing Z
// tiles (b,m,n) m-ascending; per tile: stores -> threadfence -> RELEASE
// atomicAdd(ready[b][m]). Producers ~5x faster than consumption rate.
__global__ __launch_bounds__(512, 2) void k_fused(
    const float* __restrict__ emb, const float* __restrict__ W_ih,
    const int* __restrict__ list, const int* __restrict__ cnt,
    float* __restrict__ Z, const float* __restrict__ W_hh,
    const float* __restrict__ b_ih, const float* __restrict__ b_hh,
    float* __restrict__ h_state, float* __restrict__ c_state,
    int* __restrict__ ready, int CT)
{
    __shared__ __align__(16) unsigned shm[SHDW];   // 150,016 B, role-unioned
    int bid = blockIdx.x;
    int tid = threadIdx.x;

    if (bid >= 64) {
        // =================== gemm worker ===================
        int wi = bid - 64;
        _Float16* Al = (_Float16*)shm;                 // 64 x ASTR
        _Float16* Bl = (_Float16*)(shm + 10496);       // 128 x ASTR
        int*      tl = (int*)(shm + 31488);            // 64

        for (int idx = tid; idx < 64*14; idx += 512) {
            int r = idx / 14, c2 = idx - 14*r;
            *(unsigned*)&Al[r*ASTR + 300 + 2*c2] = 0u;
        }
        for (int idx = tid; idx < 128*14; idx += 512) {
            int r = idx / 14, c2 = idx - 14*r;
            *(unsigned*)&Bl[r*ASTR + 300 + 2*c2] = 0u;
        }

        int w = tid >> 6, l = tid & 63;
        int w2 = w & 3, nh = w >> 2;
        int arow = w2*16 + (l & 15);
        int kg4  = (l >> 4) * 4;
        int drow0 = w2*16 + (l >> 4)*4;

        int MT = CT >> 6;
        for (int it = wi; it < MT*512; it += NWORK) {
            int m = it >> 9, rem = it & 511;
            int n = rem >> 6, b = rem & 63;
            int mb = cnt[b];
            int i0 = m * 64;
            if (i0 >= mb) continue;
            int n0 = n * 128;

            __syncthreads();
            if (tid < 64) {
                int jj = i0 + tid;
                tl[tid] = (jj < mb) ? list[b*CT + jj] : -1;
            }
            __syncthreads();
            for (int idx = tid; idx < 64*75; idx += 512) {
                int r = idx / 75, c = idx - 75*r;
                float4 v = {0.f, 0.f, 0.f, 0.f};
                int trow = tl[r];
                if (trow >= 0)
                    v = ((const float4*)(emb + ((size_t)b*TSTEPS + trow)*EMBED))[c];
                *(h2*)&Al[r*ASTR + 4*c]     = pack_h2(v.x, v.y);
                *(h2*)&Al[r*ASTR + 4*c + 2] = pack_h2(v.z, v.w);
            }
            for (int idx = tid; idx < 128*75; idx += 512) {
                int r = idx / 75, c = idx - 75*r;
                float4 v = ((const float4*)(W_ih + (size_t)(n0 + r)*EMBED))[c];
                *(h2*)&Bl[r*ASTR + 4*c]     = pack_h2(v.x, v.y);
                *(h2*)&Bl[r*ASTR + 4*c + 2] = pack_h2(v.z, v.w);
            }
            __syncthreads();

            f4 acc[4];
            #pragma unroll
            for (int q = 0; q < 4; ++q) acc[q] = f4{0.f, 0.f, 0.f, 0.f};

            #pragma unroll 2
            for (int ks = 0; ks < 10; ++ks) {
                int kb = ks*32 + kg4;
                h4 alo = *(const h4*)&Al[arow*ASTR + kb];
                h4 ahi = *(const h4*)&Al[arow*ASTR + kb + 16];
                h8 af = __builtin_shufflevector(alo, ahi, 0,1,2,3,4,5,6,7);
                #pragma unroll
                for (int q = 0; q < 4; ++q) {
                    int brow = (nh*4 + q)*16 + (l & 15);
                    h4 blo = *(const h4*)&Bl[brow*ASTR + kb];
                    h4 bhi = *(const h4*)&Bl[brow*ASTR + kb + 16];
                    h8 bf = __builtin_shufflevector(blo, bhi, 0,1,2,3,4,5,6,7);
                    acc[q] = __builtin_amdgcn_mfma_f32_16x16x32_f16(af, bf, acc[q], 0, 0, 0);
                }
            }

            #pragma unroll
            for (int q = 0; q < 4; ++q) {
                #pragma unroll
                for (int j = 0; j < 4; ++j) {
                    int r = drow0 + j;
                    if (i0 + r < mb)
                        Z[((size_t)b*CT + i0 + r)*GATES + n0 + (nh*4+q)*16 + (l & 15)] =
                            acc[q][j];
                }
            }
            __threadfence();
            __syncthreads();
            if (tid == 0)
                __hip_atomic_fetch_add(&ready[b*32 + m], 1,
                                       __ATOMIC_RELEASE, __HIP_MEMORY_SCOPE_AGENT);
        }
        return;
    }

    // ===================== lstm consumer (r17 structure) =====================
    int b = bid;
    unsigned* wlds  = shm;                                 // 1024*36 dwords
    float*    act13 = (float*)(shm + 36864);               // 512 floats
    _Float16* h_arr = (_Float16*)(shm + 37376);            // 256 f16

    int d    = tid & 255;
    int rowA = tid;
    int rowB = tid + 512;

    for (int idx = tid; idx < 1024*32; idx += 512) {
        int r = idx >> 5, k = idx & 31;
        float2 v = ((const float2*)(W_hh + (size_t)r*HID))[k];
        *(h2*)&wlds[r*WSTRIDE + k] = pack_h2(v.x, v.y);
    }
    h2 wrA[96], wrB[96];
    {
        const float2* pA = (const float2*)(W_hh + (size_t)rowA*HID);
        const float2* pB = (const float2*)(W_hh + (size_t)rowB*HID);
        #pragma unroll
        for (int t = 0; t < 96; ++t) {
            float2 va = pA[32 + t], vb = pB[32 + t];
            wrA[t] = pack_h2(va.x, va.y);
            wrB[t] = pack_h2(vb.x, vb.y);
        }
    }
    float biasA = b_ih[rowA] + b_hh[rowA];
    float biasB = b_ih[rowB] + b_hh[rowB];

    float c_reg = 0.f;
    if (tid < 256) {
        h_arr[d] = (_Float16)h_state[(size_t)b*HID + d];
        c_reg    = c_state[(size_t)b*HID + d];
    }
    __syncthreads();

    int mb = cnt[b];
    float zAcur = 0.f, zBcur = 0.f;
    if (mb > 0) {
        if (tid == 0) spin_tile(&ready[b*32]);
        __syncthreads();
        zAcur = Z[((size_t)b*CT)*GATES + rowA];
        zBcur = Z[((size_t)b*CT)*GATES + rowB];
    }

    for (int j = 0; j < mb; ++j) {
        int jn = j + 1;
        float zAn = 0.f, zBn = 0.f;
        if (jn < mb) {
            if ((jn & 63) == 0) {
                if (tid == 0) spin_tile(&ready[b*32 + (jn >> 6)]);
                __syncthreads();
            }
            zAn = Z[((size_t)b*CT + jn)*GATES + rowA];
            zBn = Z[((size_t)b*CT + jn)*GATES + rowB];
        }

        float accA0 = 0.f, accA1 = 0.f, accB0 = 0.f, accB1 = 0.f;
        #pragma unroll
        for (int c = 0; c < 32; ++c) {
            uint4 hv = ((const uint4*)h_arr)[c];
            h2 h0 = bc_h2(hv.x), h1 = bc_h2(hv.y);
            h2 h2_ = bc_h2(hv.z), h3 = bc_h2(hv.w);
            h2 wA0, wA1, wA2, wA3, wB0, wB1, wB2, wB3;
            if (c < 8) {
                uint4 wa = *(const uint4*)&wlds[rowA*WSTRIDE + 4*c];
                uint4 wb = *(const uint4*)&wlds[rowB*WSTRIDE + 4*c];
                wA0 = bc_h2(wa.x); wA1 = bc_h2(wa.y);
                wA2 = bc_h2(wa.z); wA3 = bc_h2(wa.w);
                wB0 = bc_h2(wb.x); wB1 = bc_h2(wb.y);
                wB2 = bc_h2(wb.z); wB3 = bc_h2(wb.w);
            } else {
                int t = (c - 8) * 4;
                wA0 = wrA[t+0]; wA1 = wrA[t+1]; wA2 = wrA[t+2]; wA3 = wrA[t+3];
                wB0 = wrB[t+0]; wB1 = wrB[t+1]; wB2 = wrB[t+2]; wB3 = wrB[t+3];
            }
            accA0 = dot2f(wA0, h0, accA0);
            accA1 = dot2f(wA1, h1, accA1);
            accA0 = dot2f(wA2, h2_, accA0);
            accA1 = dot2f(wA3, h3, accA1);
            accB0 = dot2f(wB0, h0, accB0);
            accB1 = dot2f(wB1, h1, accB1);
            accB0 = dot2f(wB2, h2_, accB0);
            accB1 = dot2f(wB3, h3, accB1);
        }
        float aF = zAcur + biasA + (accA0 + accA1);
        float aS = zBcur + biasB + (accB0 + accB1);

        float iv = 0.f, gv = 0.f;
        if (tid < 256) {
            iv = sigm_(aF);
            gv = tanh_(aS);
        } else {
            act13[d]       = sigm_(aF);   // forget gate
            act13[256 + d] = sigm_(aS);   // output gate
        }
        __syncthreads();

        if (tid < 256) {
            float fv = act13[d], ov = act13[256 + d];
            c_reg = fv * c_reg + iv * gv;
            float hn = ov * tanh_(c_reg);
            h_arr[d] = (_Float16)hn;
        }
        __syncthreads();
        zAcur = zAn; zBcur = zBn;
    }

    if (tid < 256) {
        h_state[(size_t)b*HID + d] = (float)h_arr[d];
        c_state[(size_t)b*HID + d] = c_reg;
    }
}

// ---------------- Kernel 3: logits -> softmax -> argmax ---------------------
__global__ __launch_bounds__(64) void k_final(
    const float* __restrict__ h_state, const float* __restrict__ W_out,
    const float* __restrict__ b_out, float* __restrict__ out)
{
    int b = threadIdx.x;
    float l0 = b_out[0], l1 = b_out[1];
    for (int k = 0; k < HID; ++k) {
        float h = h_state[b*HID + k];
        l0 += h * W_out[k];
        l1 += h * W_out[HID + k];
    }
    float m  = fmaxf(l0, l1);
    float e0 = expf(l0 - m), e1 = expf(l1 - m);
    float s  = e0 + e1;
    float p0 = e0 / s, p1 = e1 / s;
    out[b*2 + 0] = p0;
    out[b*2 + 1] = p1;
    out[BATCH*2 + b] = (p1 > p0) ? 1.0f : 0.0f;
}

// ---------------- host ------------------------------------------------------
extern "C" void kernel_launch(void* const* d_in, const int* in_sizes, int n_in,
                              void* d_out, int out_size, void* d_ws, size_t ws_size,
                              hipStream_t stream)
{
    (void)in_sizes; (void)n_in; (void)out_size;
    const float* emb   = (const float*)d_in[0];
    const float* mask  = (const float*)d_in[1];
    const int*   len   = (const int*)  d_in[2];
    const float* W_ih  = (const float*)d_in[3];
    const float* W_hh  = (const float*)d_in[4];
    const float* b_ih  = (const float*)d_in[5];
    const float* b_hh  = (const float*)d_in[6];
    const float* W_out = (const float*)d_in[7];
    const float* b_out = (const float*)d_in[8];
    float* out = (float*)d_out;

    char* p = (char*)d_ws;
    auto carve = [&](size_t bytes) -> char* {
        char* r = p;
        p += (bytes + 255) & ~(size_t)255;
        return r;
    };
    float* h_state = (float*)carve((size_t)BATCH*HID*4);
    float* c_state = (float*)carve((size_t)BATCH*HID*4);
    int*   cntb    = (int*)  carve((size_t)BATCH*4);
    int*   ready   = (int*)  carve((size_t)BATCH*32*4);

    size_t fixed = (size_t)(p - (char*)d_ws);
    int CT = TSTEPS;  // shrink to fit workspace
    while (CT > 64) {
        size_t lb = (((size_t)BATCH*CT*4) + 255) & ~(size_t)255;
        size_t zb = (size_t)BATCH*CT*GATES*4;
        if (fixed + lb + zb + 1024 <= ws_size) break;
        CT >>= 1;
    }
    int*   list = (int*)  carve((size_t)BATCH*CT*4);
    float* Z    = (float*)carve((size_t)BATCH*CT*GATES*4);

    int nchunks = TSTEPS / CT;
    for (int c = 0; c < nchunks; ++c) {
        int t0 = c * CT;
        int first = (c == 0) ? 1 : 0;
        hipLaunchKernelGGL(k_compact, dim3(BATCH), dim3(256), 0, stream,
                           mask, len, list, cntb, ready, h_state, c_state,
                           t0, CT, first);
        hipLaunchKernelGGL(k_fused, dim3(256), dim3(512), 0, stream,
                           emb, W_ih, list, cntb, Z, W_hh, b_ih, b_hh,
                           h_state, c_state, ready, CT);
    }
    hipLaunchKernelGGL(k_final, dim3(1), dim3(64), 0, stream,
                       h_state, W_out, b_out, out);
}

// Round 20
// 2076.579 us; speedup vs baseline: 1.1093x; 1.0254x over previous
//
#include <hip/hip_runtime.h>
#include <math.h>

#define BATCH  64
#define TSTEPS 2048
#define EMBED  300
#define HID    256
#define GATES  1024  // 4*HID
#define WSTRIDE 36   // dwords per W-LDS row: 16B-aligned rows -> b128 reads;
                     // banks (4l+4c)%32 distinct within each 8-lane phase
#define ASTR   328   // f16 stride of k_gemm staged tiles (300 data + 28 pad)

typedef __fp16 h2 __attribute__((ext_vector_type(2)));   // matches cvt_pkrtz/fdot2
typedef __fp16 h4 __attribute__((ext_vector_type(4)));
typedef __fp16 h8 __attribute__((ext_vector_type(8)));
typedef float  f4 __attribute__((ext_vector_type(4)));

__device__ __forceinline__ h2 pack_h2(float a, float b) {
    return __builtin_amdgcn_cvt_pkrtz(a, b);
}
__device__ __forceinline__ h2 bc_h2(unsigned u) {
    return __builtin_bit_cast(h2, u);
}
__device__ __forceinline__ float dot2f(h2 w, h2 h, float acc) {
#if __has_builtin(__builtin_amdgcn_fdot2)
    return __builtin_amdgcn_fdot2(w, h, acc, false);   // f32 accumulate
#else
    return acc + (float)w[0]*(float)h[0] + (float)w[1]*(float)h[1];
#endif
}
__device__ __forceinline__ float rcpf_(float x) {
#if __has_builtin(__builtin_amdgcn_rcpf)
    return __builtin_amdgcn_rcpf(x);
#else
    return 1.0f / x;
#endif
}
__device__ __forceinline__ float sigm_(float x) { return rcpf_(1.f + __expf(-x)); }
__device__ __forceinline__ float tanh_(float x) { return 1.f - 2.f*rcpf_(__expf(2.f*x) + 1.f); }

// ---------------- Kernel 1: per-chunk compaction of update steps ------------
__global__ __launch_bounds__(256) void k_compact(
    const float* __restrict__ mask, const int* __restrict__ lengths,
    int* __restrict__ list, int* __restrict__ cnt,
    float* __restrict__ h_state, float* __restrict__ c_state,
    int t0, int CT, int first_chunk)
{
    int b = blockIdx.x, tid = threadIdx.x;
    if (first_chunk) {
        h_state[b*HID + tid] = 0.f;   // blockDim == HID
        c_state[b*HID + tid] = 0.f;
    }
    int idx = lengths[b] - 1;
    idx = idx < 0 ? 0 : (idx > TSTEPS-1 ? TSTEPS-1 : idx);

    __shared__ int wcnt[4];
    __shared__ int running;
    if (tid == 0) running = 0;
    __syncthreads();

    for (int base = 0; base < CT; base += 256) {
        int t = t0 + base + tid;
        bool pred = ((base + tid) < CT) && (t <= idx)
                    && (mask[b*TSTEPS + t] >= 0.5f);
        unsigned long long bal = __ballot(pred);
        int wave = tid >> 6, lane = tid & 63;
        if (lane == 0) wcnt[wave] = __popcll(bal);
        __syncthreads();
        int off = running;
        for (int w2 = 0; w2 < wave; ++w2) off += wcnt[w2];
        off += __popcll(bal & ((1ull << lane) - 1ull));
        if (pred) list[b*CT + off] = t;
        __syncthreads();
        if (tid == 0) running += wcnt[0] + wcnt[1] + wcnt[2] + wcnt[3];
        __syncthreads();
    }
    if (tid == 0) cnt[b] = running;
}

// ---------------- Kernel 2: gathered GEMM via MFMA, persistent-B ------------
// r14 structure (measured best): grid (8 n-tiles, 1, 64 batches) = 512 blocks.
// Each block stages its B tile (W_ih rows n0..n0+127 as f16) ONCE, then loops
// over M-tiles of 64 gathered rows. Z stays f32 (r18 proved f16-Z slows the
// lstm consumer more than the byte savings help).
__global__ __launch_bounds__(256) void k_gemm(
    const float* __restrict__ emb, const float* __restrict__ W_ih,
    const int* __restrict__ list, const int* __restrict__ cnt,
    float* __restrict__ Z, int CT)
{
    int b = blockIdx.z;
    int mb = cnt[b];
    int n0 = blockIdx.x * 128;
    int tid = threadIdx.x;
    int w = tid >> 6, l = tid & 63;

    __shared__ _Float16 Al[64 * ASTR];     // 41,984 B
    __shared__ _Float16 Bl[128 * ASTR];    // 83,968 B
    __shared__ int tl[64];

    for (int idx = tid; idx < 128*75; idx += 256) {
        int r = idx / 75, c = idx - 75*r;
        float4 v = ((const float4*)(W_ih + (size_t)(n0 + r)*EMBED))[c];
        *(h2*)&Bl[r*ASTR + 4*c]     = pack_h2(v.x, v.y);
        *(h2*)&Bl[r*ASTR + 4*c + 2] = pack_h2(v.z, v.w);
    }
    for (int idx = tid; idx < 128*14; idx += 256) {
        int r = idx / 14, c2 = idx - 14*r;
        *(unsigned*)&Bl[r*ASTR + 300 + 2*c2] = 0u;
    }
    for (int idx = tid; idx < 64*14; idx += 256) {
        int r = idx / 14, c2 = idx - 14*r;
        *(unsigned*)&Al[r*ASTR + 300 + 2*c2] = 0u;   // pad written once
    }

    int arow = w*16 + (l & 15);
    int kg4  = (l >> 4) * 4;
    int drow0 = w*16 + (l >> 4)*4;

    for (int i0 = 0; i0 < mb; i0 += 64) {
        __syncthreads();           // prev MFMA done -> Al/tl reusable; B ready
        if (tid < 64) {
            int j = i0 + tid;
            tl[tid] = (j < mb) ? list[b*CT + j] : -1;
        }
        __syncthreads();           // tl visible
        for (int idx = tid; idx < 64*75; idx += 256) {
            int r = idx / 75, c = idx - 75*r;
            float4 v = {0.f, 0.f, 0.f, 0.f};
            int trow = tl[r];
            if (trow >= 0)
                v = ((const float4*)(emb + ((size_t)b*TSTEPS + trow)*EMBED))[c];
            *(h2*)&Al[r*ASTR + 4*c]     = pack_h2(v.x, v.y);
            *(h2*)&Al[r*ASTR + 4*c + 2] = pack_h2(v.z, v.w);
        }
        __syncthreads();           // Al visible

        f4 acc[8];
        #pragma unroll
        for (int nt = 0; nt < 8; ++nt) acc[nt] = f4{0.f, 0.f, 0.f, 0.f};

        #pragma unroll 2
        for (int ks = 0; ks < 10; ++ks) {
            int kb = ks*32 + kg4;
            h4 alo = *(const h4*)&Al[arow*ASTR + kb];
            h4 ahi = *(const h4*)&Al[arow*ASTR + kb + 16];
            h8 af = __builtin_shufflevector(alo, ahi, 0,1,2,3,4,5,6,7);
            #pragma unroll
            for (int nt = 0; nt < 8; ++nt) {
                int brow = nt*16 + (l & 15);
                h4 blo = *(const h4*)&Bl[brow*ASTR + kb];
                h4 bhi = *(const h4*)&Bl[brow*ASTR + kb + 16];
                h8 bf = __builtin_shufflevector(blo, bhi, 0,1,2,3,4,5,6,7);
                acc[nt] = __builtin_amdgcn_mfma_f32_16x16x32_f16(af, bf, acc[nt], 0, 0, 0);
            }
        }

        #pragma unroll
        for (int nt = 0; nt < 8; ++nt) {
            #pragma unroll
            for (int j = 0; j < 4; ++j) {
                int r = drow0 + j;
                if (i0 + r < mb)
                    Z[((size_t)b*CT + i0 + r)*GATES + n0 + nt*16 + (l & 15)] = acc[nt][j];
            }
        }
    }
}

// ---------------- Kernel 3: recurrent LSTM — ONE block per batch ------------
// EXACT r17 champion (measured 1735us; best of 7 structural variants):
// 512 threads; thread i owns gate-rows {i, 512+i}. W_hh f16: k<64 in LDS
// (WSTRIDE=36, b128 conflict-free reads), k in [64,256) as 2x96 h2 AGPR-
// resident (the proven compiler placement cap). 2 barriers, native
// activations, 1-step z prefetch. DS-issue-bound at ~4070 cy/step on an
// irreducibly serial chain — 7 restructures confirmed this is the floor.
__global__ __launch_bounds__(512, 2) void k_lstm(
    const float* __restrict__ Z, const int* __restrict__ cnt,
    const float* __restrict__ W_hh,
    const float* __restrict__ b_ih, const float* __restrict__ b_hh,
    float* __restrict__ h_state, float* __restrict__ c_state, int CT)
{
    int b = blockIdx.x;
    int tid = threadIdx.x;            // 0..511
    int d   = tid & 255;              // hidden dim this thread's rows act on
    int rowA = tid;                   // gate (tid>>8)      : 0 or 1
    int rowB = tid + 512;             // gate (tid>>8) + 2  : 2 or 3

    __shared__ __align__(16) unsigned wlds[1024 * WSTRIDE];  // 147,456 B
    __shared__ float act13[2][256];                  // forget, out broadcast
    __shared__ __align__(16) _Float16 h_arr[HID];    // current h (f16)

    // ---- stage W[k<64] into LDS as f16 pairs --------------------------------
    for (int idx = tid; idx < 1024*32; idx += 512) {
        int r = idx >> 5, k = idx & 31;              // k = half2 index (f16 2k,2k+1)
        float2 v = ((const float2*)(W_hh + (size_t)r*HID))[k];
        *(h2*)&wlds[r*WSTRIDE + k] = pack_h2(v.x, v.y);
    }

    // ---- W[k in 64..255] into registers: 96 half2 per row -------------------
    h2 wrA[96], wrB[96];
    {
        const float2* pA = (const float2*)(W_hh + (size_t)rowA*HID);
        const float2* pB = (const float2*)(W_hh + (size_t)rowB*HID);
        #pragma unroll
        for (int t = 0; t < 96; ++t) {
            float2 va = pA[32 + t], vb = pB[32 + t];
            wrA[t] = pack_h2(va.x, va.y);
            wrB[t] = pack_h2(vb.x, vb.y);
        }
    }
    float biasA = b_ih[rowA] + b_hh[rowA];
    float biasB = b_ih[rowB] + b_hh[rowB];

    float c_reg = 0.f;
    if (tid < 256) {
        h_arr[d] = (_Float16)h_state[(size_t)b*HID + d];
        c_reg    = c_state[(size_t)b*HID + d];
    }
    __syncthreads();

    int mb = cnt[b];
    float zAcur = 0.f, zBcur = 0.f;
    if (mb > 0) {
        zAcur = Z[((size_t)b*CT)*GATES + rowA];
        zBcur = Z[((size_t)b*CT)*GATES + rowB];
    }

    for (int j = 0; j < mb; ++j) {
        // prefetch next step's z under the dot
        float zAn = 0.f, zBn = 0.f;
        if (j + 1 < mb) {
            zAn = Z[((size_t)b*CT + j + 1)*GATES + rowA];
            zBn = Z[((size_t)b*CT + j + 1)*GATES + rowB];
        }

        float accA0 = 0.f, accA1 = 0.f, accB0 = 0.f, accB1 = 0.f;
        #pragma unroll
        for (int c = 0; c < 32; ++c) {
            uint4 hv = ((const uint4*)h_arr)[c];     // 8 f16 of h (broadcast)
            h2 h0 = bc_h2(hv.x), h1 = bc_h2(hv.y);
            h2 h2_ = bc_h2(hv.z), h3 = bc_h2(hv.w);
            h2 wA0, wA1, wA2, wA3, wB0, wB1, wB2, wB3;
            if (c < 8) {
                uint4 wa = *(const uint4*)&wlds[rowA*WSTRIDE + 4*c];   // b128
                uint4 wb = *(const uint4*)&wlds[rowB*WSTRIDE + 4*c];   // b128
                wA0 = bc_h2(wa.x); wA1 = bc_h2(wa.y);
                wA2 = bc_h2(wa.z); wA3 = bc_h2(wa.w);
                wB0 = bc_h2(wb.x); wB1 = bc_h2(wb.y);
                wB2 = bc_h2(wb.z); wB3 = bc_h2(wb.w);
            } else {
                int t = (c - 8) * 4;
                wA0 = wrA[t+0]; wA1 = wrA[t+1]; wA2 = wrA[t+2]; wA3 = wrA[t+3];
                wB0 = wrB[t+0]; wB1 = wrB[t+1]; wB2 = wrB[t+2]; wB3 = wrB[t+3];
            }
            accA0 = dot2f(wA0, h0, accA0);
            accA1 = dot2f(wA1, h1, accA1);
            accA0 = dot2f(wA2, h2_, accA0);
            accA1 = dot2f(wA3, h3, accA1);
            accB0 = dot2f(wB0, h0, accB0);
            accB1 = dot2f(wB1, h1, accB1);
            accB0 = dot2f(wB2, h2_, accB0);
            accB1 = dot2f(wB3, h3, accB1);
        }
        float aF = zAcur + biasA + (accA0 + accA1);   // gate input(i<256)/forget
        float aS = zBcur + biasB + (accB0 + accB1);   // gate cellcand / out

        float iv = 0.f, gv = 0.f;
        if (tid < 256) {
            iv = sigm_(aF);                 // input gate
            gv = tanh_(aS);                 // cell candidate
        } else {
            act13[0][d] = sigm_(aF);        // forget gate
            act13[1][d] = sigm_(aS);        // output gate
        }
        __syncthreads();   // act13 ready; everyone done reading h_arr

        if (tid < 256) {
            float fv = act13[0][d], ov = act13[1][d];
            c_reg = fv * c_reg + iv * gv;
            float hn = ov * tanh_(c_reg);
            h_arr[d] = (_Float16)hn;
        }
        __syncthreads();   // h_arr ready for next step
        zAcur = zAn; zBcur = zBn;
    }

    if (tid < 256) {
        h_state[(size_t)b*HID + d] = (float)h_arr[d];
        c_state[(size_t)b*HID + d] = c_reg;
    }
}

// ---------------- Kernel 4: logits -> softmax -> argmax ---------------------
__global__ __launch_bounds__(64) void k_final(
    const float* __restrict__ h_state, const float* __restrict__ W_out,
    const float* __restrict__ b_out, float* __restrict__ out)
{
    int b = threadIdx.x;   // 64 threads
    float l0 = b_out[0], l1 = b_out[1];
    for (int k = 0; k < HID; ++k) {
        float h = h_state[b*HID + k];
        l0 += h * W_out[k];
        l1 += h * W_out[HID + k];
    }
    float m  = fmaxf(l0, l1);
    float e0 = expf(l0 - m), e1 = expf(l1 - m);
    float s  = e0 + e1;
    float p0 = e0 / s, p1 = e1 / s;
    out[b*2 + 0] = p0;
    out[b*2 + 1] = p1;
    out[BATCH*2 + b] = (p1 > p0) ? 1.0f : 0.0f;  // argmax, first-index tiebreak
}

// ---------------- host ------------------------------------------------------
extern "C" void kernel_launch(void* const* d_in, const int* in_sizes, int n_in,
                              void* d_out, int out_size, void* d_ws, size_t ws_size,
                              hipStream_t stream)
{
    (void)in_sizes; (void)n_in; (void)out_size;
    const float* emb   = (const float*)d_in[0];
    const float* mask  = (const float*)d_in[1];
    const int*   len   = (const int*)  d_in[2];
    const float* W_ih  = (const float*)d_in[3];
    const float* W_hh  = (const float*)d_in[4];
    const float* b_ih  = (const float*)d_in[5];
    const float* b_hh  = (const float*)d_in[6];
    const float* W_out = (const float*)d_in[7];
    const float* b_out = (const float*)d_in[8];
    float* out = (float*)d_out;

    char* p = (char*)d_ws;
    auto carve = [&](size_t bytes) -> char* {
        char* r = p;
        p += (bytes + 255) & ~(size_t)255;
        return r;
    };
    float* h_state = (float*)carve((size_t)BATCH*HID*4);
    float* c_state = (float*)carve((size_t)BATCH*HID*4);
    int*   cntb    = (int*)  carve((size_t)BATCH*4);

    size_t fixed = (size_t)(p - (char*)d_ws);
    int CT = TSTEPS;  // shrink to fit workspace
    while (CT > 64) {
        size_t lb = (((size_t)BATCH*CT*4) + 255) & ~(size_t)255;
        size_t zb = (size_t)BATCH*CT*GATES*4;
        if (fixed + lb + zb + 1024 <= ws_size) break;
        CT >>= 1;
    }
    int*   list = (int*)  carve((size_t)BATCH*CT*4);
    float* Z    = (float*)carve((size_t)BATCH*CT*GATES*4);

    int nchunks = TSTEPS / CT;
    for (int c = 0; c < nchunks; ++c) {
        int t0 = c * CT;
        int first = (c == 0) ? 1 : 0;
        hipLaunchKernelGGL(k_compact, dim3(BATCH), dim3(256), 0, stream,
                           mask, len, list, cntb, h_state, c_state,
                           t0, CT, first);
        hipLaunchKernelGGL(k_gemm, dim3(8, 1, BATCH), dim3(256), 0, stream,
                           emb, W_ih, list, cntb, Z, CT);
        hipLaunchKernelGGL(k_lstm, dim3(BATCH), dim3(512), 0, stream,
                           Z, cntb, W_hh, b_ih, b_hh,
                           h_state, c_state, CT);
    }
    hipLaunchKernelGGL(k_final, dim3(1), dim3(64), 0, stream,
                       h_state, W_out, b_out, out);
}